// Round 1
// baseline (268.205 us; speedup 1.0000x reference)
//
#include <hip/hip_runtime.h>
#include <hip/hip_bf16.h>

// RGCN layer, MI355X (gfx950).
// Algorithm: 3-stage transform-then-gather.
//   Stage 1: X[n, r, o] = sum_d nf[n,d] * W[r,d,o]   (bf16 MFMA GEMM, X stored bf16)
//   Stage 2: per edge e: acc[dst_e, :] += norm_e * X[src_e, etype_e, :]  (atomicAdd)
//   Stage 3: out = relu(acc + bias)
// ws layout: [0, 12.8MB) fp32 acc ; [12.8MB, 115.2MB) bf16 X.

#define NN 50000
#define EE 1000000
#define RR 16

typedef __attribute__((ext_vector_type(8))) short short8;
typedef __attribute__((ext_vector_type(4))) float f32x4;

static __device__ inline unsigned short f2bf(float f) {
  __hip_bfloat16 h = __float2bfloat16(f);
  union { __hip_bfloat16 h; unsigned short u; } cv;
  cv.h = h;
  return cv.u;
}
static __device__ inline float bf2f(unsigned short u) {
  union { unsigned int i; float f; } cv;
  cv.i = ((unsigned int)u) << 16;
  return cv.f;
}

// Stage 1: block = 256 threads (4 waves), handles 256 nodes x 1 relation.
// W_r staged transposed in LDS as [o][k] with pad 72 (144B row = 36 banks ->
// ds_read_b128 across lr-lanes lands on distinct 4-bank groups, 2-way = free).
// MFMA 16x16x32 bf16: A row = lane&15, k = (lane>>4)*8+j ; C/D col = lane&15,
// row = (lane>>4)*4 + reg  [m89-verified mapping].
__global__ __launch_bounds__(256) void k_gemm(const float* __restrict__ nf,
                                              const float* __restrict__ W,
                                              unsigned short* __restrict__ X) {
  __shared__ __align__(16) unsigned short Wl[64][72];
  const int r = blockIdx.y;
  const int tid = threadIdx.x;
  for (int i = tid; i < 4096; i += 256) {
    // weight[r, k, o] at r*4096 + k*64 + o  ->  Wl[o][k]
    Wl[i & 63][i >> 6] = f2bf(W[(r << 12) + i]);
  }
  __syncthreads();
  const int lane = tid & 63;
  const int wv = tid >> 6;
  const int lr = lane & 15, lg = lane >> 4;
  #pragma unroll
  for (int st = 0; st < 4; ++st) {
    const int n0 = (blockIdx.x << 8) + ((wv * 4 + st) << 4);
    short8 a0, a1;
    const int arow = n0 + lr;
    if (arow < NN) {
      const float* ap = nf + arow * 64 + lg * 8;
      float4 v0 = *reinterpret_cast<const float4*>(ap);
      float4 v1 = *reinterpret_cast<const float4*>(ap + 4);
      float4 v2 = *reinterpret_cast<const float4*>(ap + 32);
      float4 v3 = *reinterpret_cast<const float4*>(ap + 36);
      a0 = short8{(short)f2bf(v0.x), (short)f2bf(v0.y), (short)f2bf(v0.z), (short)f2bf(v0.w),
                  (short)f2bf(v1.x), (short)f2bf(v1.y), (short)f2bf(v1.z), (short)f2bf(v1.w)};
      a1 = short8{(short)f2bf(v2.x), (short)f2bf(v2.y), (short)f2bf(v2.z), (short)f2bf(v2.w),
                  (short)f2bf(v3.x), (short)f2bf(v3.y), (short)f2bf(v3.z), (short)f2bf(v3.w)};
    } else {
      a0 = short8{0, 0, 0, 0, 0, 0, 0, 0};
      a1 = a0;
    }
    #pragma unroll
    for (int c = 0; c < 4; ++c) {
      f32x4 acc = {0.f, 0.f, 0.f, 0.f};
      const int o = c * 16 + lr;  // B col = lane&15
      short8 b0 = *reinterpret_cast<const short8*>(&Wl[o][lg * 8]);
      short8 b1 = *reinterpret_cast<const short8*>(&Wl[o][32 + lg * 8]);
      acc = __builtin_amdgcn_mfma_f32_16x16x32_bf16(a0, b0, acc, 0, 0, 0);
      acc = __builtin_amdgcn_mfma_f32_16x16x32_bf16(a1, b1, acc, 0, 0, 0);
      #pragma unroll
      for (int i = 0; i < 4; ++i) {
        const int node = n0 + lg * 4 + i;  // C row = (lane>>4)*4 + reg
        if (node < NN)
          X[(size_t)node * 1024 + (r << 6) + c * 16 + lr] = f2bf(acc[i]);
      }
    }
  }
}

// Stage 2: one wave per edge (lane = output dim), grid-stride over edges.
__global__ __launch_bounds__(256) void k_edge(const int* __restrict__ esrc,
                                              const int* __restrict__ edst,
                                              const int* __restrict__ etyp,
                                              const float* __restrict__ enorm,
                                              const unsigned short* __restrict__ X,
                                              float* __restrict__ acc) {
  const int lane = threadIdx.x & 63;
  int w = (int)((blockIdx.x * blockDim.x + threadIdx.x) >> 6);
  const int nw = (int)((gridDim.x * blockDim.x) >> 6);
  for (int e = w; e < EE; e += nw) {
    const int s = esrc[e], d = edst[e], t = etyp[e];
    const float nm = enorm[e];
    const float v = bf2f(X[(size_t)s * 1024 + (t << 6) + lane]) * nm;
    atomicAdd(&acc[(size_t)d * 64 + lane], v);
  }
}

// Stage 3: out = relu(acc + bias), float4-vectorized. 800000 float4s.
__global__ __launch_bounds__(256) void k_finish(const float* __restrict__ acc,
                                                const float* __restrict__ bias,
                                                float* __restrict__ out) {
  const int i = blockIdx.x * 256 + threadIdx.x;
  if (i < 800000) {
    const float4 a = reinterpret_cast<const float4*>(acc)[i];
    const float4 b = reinterpret_cast<const float4*>(bias)[i & 15];
    float4 o;
    o.x = fmaxf(a.x + b.x, 0.f);
    o.y = fmaxf(a.y + b.y, 0.f);
    o.z = fmaxf(a.z + b.z, 0.f);
    o.w = fmaxf(a.w + b.w, 0.f);
    reinterpret_cast<float4*>(out)[i] = o;
  }
}

extern "C" void kernel_launch(void* const* d_in, const int* in_sizes, int n_in,
                              void* d_out, int out_size, void* d_ws, size_t ws_size,
                              hipStream_t stream) {
  const float* nf = (const float*)d_in[0];
  const int* esrc = (const int*)d_in[1];
  const int* edst = (const int*)d_in[2];
  const int* etyp = (const int*)d_in[3];
  const float* enorm = (const float*)d_in[4];
  const float* W = (const float*)d_in[5];
  const float* bias = (const float*)d_in[6];
  float* out = (float*)d_out;

  float* acc = (float*)d_ws;                                        // 12.8 MB
  unsigned short* X = (unsigned short*)((char*)d_ws + (size_t)NN * 64 * 4);  // 102.4 MB

  hipMemsetAsync(acc, 0, (size_t)NN * 64 * 4, stream);
  dim3 g1((NN + 255) / 256, RR);
  k_gemm<<<g1, 256, 0, stream>>>(nf, W, X);
  k_edge<<<2048, 256, 0, stream>>>(esrc, edst, etyp, enorm, X, acc);
  k_finish<<<(800000 + 255) / 256, 256, 0, stream>>>(acc, bias, out);
}

// Round 2
// 208.294 us; speedup vs baseline: 1.2876x; 1.2876x over previous
//
#include <hip/hip_runtime.h>
#include <hip/hip_bf16.h>

// RGCN layer, MI355X (gfx950).
// Stage 1: X[n, r, o] = sum_d nf[n,d] * W[r,d,o]   (bf16 MFMA GEMM, X stored bf16)
// Stage 2: build dst-CSR on device (hist + scan + scatter of packed edge recs)
// Stage 3: wave-per-node gather: out[n,:] = relu(sum_{e: dst=n} norm_e * X[src_e, typ_e, :] + bias)
// No per-element atomics on the output (R1 showed 250MB HBM write-through from 64M atomicAdds).
//
// ws layout: [0, 102.4MB) bf16 X ; then rec (8MB uint2) ; offs (200KB) ; cnt/cursor (200KB) ; bsum.

#define NN 50000
#define EE 1000000
#define RR 16
#define NB 196  // ceil(NN/256)

typedef __attribute__((ext_vector_type(8))) short short8;
typedef __attribute__((ext_vector_type(4))) float f32x4;

static __device__ inline unsigned short f2bf(float f) {
  union { __hip_bfloat16 h; unsigned short u; } cv;
  cv.h = __float2bfloat16(f);
  return cv.u;
}
static __device__ inline float bf2f(unsigned short u) {
  union { unsigned int i; float f; } cv;
  cv.i = ((unsigned int)u) << 16;
  return cv.f;
}

// ---------------- Stage 1: dense transform (unchanged from R1) ----------------
__global__ __launch_bounds__(256) void k_gemm(const float* __restrict__ nf,
                                              const float* __restrict__ W,
                                              unsigned short* __restrict__ X) {
  __shared__ __align__(16) unsigned short Wl[64][72];
  const int r = blockIdx.y;
  const int tid = threadIdx.x;
  for (int i = tid; i < 4096; i += 256) {
    Wl[i & 63][i >> 6] = f2bf(W[(r << 12) + i]);  // weight[r,k,o] -> Wl[o][k]
  }
  __syncthreads();
  const int lane = tid & 63;
  const int wv = tid >> 6;
  const int lr = lane & 15, lg = lane >> 4;
  #pragma unroll
  for (int st = 0; st < 4; ++st) {
    const int n0 = (blockIdx.x << 8) + ((wv * 4 + st) << 4);
    short8 a0, a1;
    const int arow = n0 + lr;
    if (arow < NN) {
      const float* ap = nf + arow * 64 + lg * 8;
      float4 v0 = *reinterpret_cast<const float4*>(ap);
      float4 v1 = *reinterpret_cast<const float4*>(ap + 4);
      float4 v2 = *reinterpret_cast<const float4*>(ap + 32);
      float4 v3 = *reinterpret_cast<const float4*>(ap + 36);
      a0 = short8{(short)f2bf(v0.x), (short)f2bf(v0.y), (short)f2bf(v0.z), (short)f2bf(v0.w),
                  (short)f2bf(v1.x), (short)f2bf(v1.y), (short)f2bf(v1.z), (short)f2bf(v1.w)};
      a1 = short8{(short)f2bf(v2.x), (short)f2bf(v2.y), (short)f2bf(v2.z), (short)f2bf(v2.w),
                  (short)f2bf(v3.x), (short)f2bf(v3.y), (short)f2bf(v3.z), (short)f2bf(v3.w)};
    } else {
      a0 = short8{0, 0, 0, 0, 0, 0, 0, 0};
      a1 = a0;
    }
    #pragma unroll
    for (int c = 0; c < 4; ++c) {
      f32x4 acc = {0.f, 0.f, 0.f, 0.f};
      const int o = c * 16 + lr;
      short8 b0 = *reinterpret_cast<const short8*>(&Wl[o][lg * 8]);
      short8 b1 = *reinterpret_cast<const short8*>(&Wl[o][32 + lg * 8]);
      acc = __builtin_amdgcn_mfma_f32_16x16x32_bf16(a0, b0, acc, 0, 0, 0);
      acc = __builtin_amdgcn_mfma_f32_16x16x32_bf16(a1, b1, acc, 0, 0, 0);
      #pragma unroll
      for (int i = 0; i < 4; ++i) {
        const int node = n0 + lg * 4 + i;
        if (node < NN)
          X[(size_t)node * 1024 + (r << 6) + c * 16 + lr] = f2bf(acc[i]);
      }
    }
  }
}

// ---------------- Stage 2: CSR build ----------------
__global__ __launch_bounds__(256) void k_hist(const int* __restrict__ edst,
                                              int* __restrict__ cnt) {
  const int e = blockIdx.x * 256 + threadIdx.x;
  if (e < EE) atomicAdd(&cnt[edst[e]], 1);
}

__global__ __launch_bounds__(256) void k_scan_a(const int* __restrict__ cnt,
                                                int* __restrict__ offs,
                                                int* __restrict__ bsum) {
  __shared__ int s[256];
  const int t = threadIdx.x;
  const int i = blockIdx.x * 256 + t;
  const int v = (i < NN) ? cnt[i] : 0;
  s[t] = v;
  __syncthreads();
  #pragma unroll
  for (int off = 1; off < 256; off <<= 1) {
    const int x = (t >= off) ? s[t - off] : 0;
    __syncthreads();
    s[t] += x;
    __syncthreads();
  }
  if (i < NN) offs[i] = s[t] - v;  // exclusive within block
  if (t == 255) bsum[blockIdx.x] = s[255];
}

__global__ __launch_bounds__(256) void k_scan_b(int* __restrict__ bsum) {
  __shared__ int s[256];
  const int t = threadIdx.x;
  const int v = (t < NB) ? bsum[t] : 0;
  s[t] = v;
  __syncthreads();
  #pragma unroll
  for (int off = 1; off < 256; off <<= 1) {
    const int x = (t >= off) ? s[t - off] : 0;
    __syncthreads();
    s[t] += x;
    __syncthreads();
  }
  if (t < NB) bsum[t] = s[t] - v;  // exclusive over blocks
}

__global__ __launch_bounds__(256) void k_scan_c(int* __restrict__ offs,
                                                const int* __restrict__ bsum,
                                                int* __restrict__ cur) {
  const int i = blockIdx.x * 256 + threadIdx.x;
  if (i < NN) {
    const int o = offs[i] + bsum[blockIdx.x];
    offs[i] = o;
    cur[i] = o;
  }
  if (i == 0) offs[NN] = EE;
}

__global__ __launch_bounds__(256) void k_scatter(const int* __restrict__ esrc,
                                                 const int* __restrict__ edst,
                                                 const int* __restrict__ etyp,
                                                 const float* __restrict__ enorm,
                                                 int* __restrict__ cur,
                                                 uint2* __restrict__ rec) {
  const int e = blockIdx.x * 256 + threadIdx.x;
  if (e < EE) {
    const int pos = atomicAdd(&cur[edst[e]], 1);
    rec[pos] = make_uint2((unsigned)(esrc[e] * 16 + etyp[e]), __float_as_uint(enorm[e]));
  }
}

// ---------------- Stage 3: wave-per-node gather + bias + relu ----------------
__global__ __launch_bounds__(256) void k_gather(const uint2* __restrict__ rec,
                                                const int* __restrict__ offs,
                                                const unsigned short* __restrict__ X,
                                                const float* __restrict__ bias,
                                                float* __restrict__ out) {
  const int w = (int)((blockIdx.x * 256 + threadIdx.x) >> 6);  // node id
  const int lane = threadIdx.x & 63;
  if (w >= NN) return;
  int j = offs[w];
  const int end = offs[w + 1];
  float a = 0.f;
  // unroll-by-4: 4 independent 128B row loads in flight per iteration
  for (; j + 4 <= end; j += 4) {
    const uint2 r0 = rec[j], r1 = rec[j + 1], r2 = rec[j + 2], r3 = rec[j + 3];
    const float x0 = bf2f(X[(size_t)r0.x * 64 + lane]);
    const float x1 = bf2f(X[(size_t)r1.x * 64 + lane]);
    const float x2 = bf2f(X[(size_t)r2.x * 64 + lane]);
    const float x3 = bf2f(X[(size_t)r3.x * 64 + lane]);
    a += __uint_as_float(r0.y) * x0 + __uint_as_float(r1.y) * x1 +
         __uint_as_float(r2.y) * x2 + __uint_as_float(r3.y) * x3;
  }
  for (; j < end; ++j) {
    const uint2 r = rec[j];
    a += __uint_as_float(r.y) * bf2f(X[(size_t)r.x * 64 + lane]);
  }
  out[(size_t)w * 64 + lane] = fmaxf(a + bias[lane], 0.f);
}

extern "C" void kernel_launch(void* const* d_in, const int* in_sizes, int n_in,
                              void* d_out, int out_size, void* d_ws, size_t ws_size,
                              hipStream_t stream) {
  const float* nf = (const float*)d_in[0];
  const int* esrc = (const int*)d_in[1];
  const int* edst = (const int*)d_in[2];
  const int* etyp = (const int*)d_in[3];
  const float* enorm = (const float*)d_in[4];
  const float* W = (const float*)d_in[5];
  const float* bias = (const float*)d_in[6];
  float* out = (float*)d_out;

  char* ws = (char*)d_ws;
  unsigned short* X = (unsigned short*)ws;                 // 102,400,000 B
  uint2* rec = (uint2*)(ws + 102400000);                   //   8,000,000 B
  int* offs = (int*)(ws + 110400000);                      //     200,004 B
  int* cnt = (int*)(ws + 110600008);                       //     200,000 B (cnt, then cursor)
  int* bsum = (int*)(ws + 110800008);                      //         784 B

  hipMemsetAsync(cnt, 0, NN * 4, stream);

  dim3 g1((NN + 255) / 256, RR);
  k_gemm<<<g1, 256, 0, stream>>>(nf, W, X);

  k_hist<<<(EE + 255) / 256, 256, 0, stream>>>(edst, cnt);
  k_scan_a<<<NB, 256, 0, stream>>>(cnt, offs, bsum);
  k_scan_b<<<1, 256, 0, stream>>>(bsum);
  k_scan_c<<<NB, 256, 0, stream>>>(offs, bsum, cnt);  // cnt becomes cursor
  k_scatter<<<(EE + 255) / 256, 256, 0, stream>>>(esrc, edst, etyp, enorm, cnt, rec);

  k_gather<<<(NN * 64 + 255) / 256, 256, 0, stream>>>(rec, offs, X, bias, out);
}